// Round 4
// baseline (377.064 us; speedup 1.0000x reference)
//
#include <hip/hip_runtime.h>
#include <hip/hip_bf16.h>

typedef float f32x4 __attribute__((ext_vector_type(4)));
typedef short s16x8 __attribute__((ext_vector_type(8)));
typedef short s16x4 __attribute__((ext_vector_type(4)));
typedef __bf16 bf16x8 __attribute__((ext_vector_type(8)));
typedef unsigned short u16;

#define DEVI __device__ __forceinline__

static constexpr int    HW      = 16384;
static constexpr size_t BSTRIDE = (size_t)256 * HW;

// ---- workspace byte offsets ----
static constexpr size_t oXBT   = 0;                                    // bf16 [8][HW][256]
static constexpr size_t oEK    = oXBT  + (size_t)8 * HW * 256 * 2;     // bf16 [8][256][HW] exp(keys)
static constexpr size_t oQT    = oEK   + (size_t)8 * 256 * HW * 2;     // bf16 [8][HW][256] softmaxed Q, transposed
static constexpr size_t oVB    = oQT   + (size_t)8 * HW * 256 * 2;     // bf16 [8][256][HW]
static constexpr size_t oWK    = oVB   + (size_t)8 * 256 * HW * 2;     // bf16 [768][256]
static constexpr size_t oBIAS  = oWK   + (size_t)768 * 256 * 2;        // f32 [768]
static constexpr size_t oISE   = oBIAS + 4096;                         // f32 [8][256] inv row-sum-exp
static constexpr size_t oPS    = oISE  + 8192;                         // f32 [256][8][256] rowsum partials
static constexpr size_t oCTX   = oPS   + (size_t)256 * 2048 * 4;       // f32 [64][32][32]
static constexpr size_t oMB    = oCTX  + (size_t)64 * 1024 * 4;        // bf16 [8][256][256]
static constexpr size_t oCPART = oMB   + (size_t)8 * 256 * 256 * 2;    // f32 [4096][1024]
static constexpr size_t oMPART = oCPART + (size_t)4096 * 1024 * 4;     // f32 [8][8][HW]

DEVI float bf2f(short x) {
  unsigned u = ((unsigned)(unsigned short)x) << 16;
  return __builtin_bit_cast(float, u);
}
DEVI u16 f2bf(float x) { return __builtin_bit_cast(u16, (__bf16)x); }

DEVI void gld16(const void* g, void* l) {
  __builtin_amdgcn_global_load_lds(
      (__attribute__((address_space(1))) void*)(g),
      (__attribute__((address_space(3))) void*)(l), 16, 0, 0);
}

// ---------------- prep: pack Wk|Wq|Wv -> bf16 [768][256], biases -> f32 [768] ----------------
__global__ __launch_bounds__(256) void k_prep(
    const float* __restrict__ Wk, const float* __restrict__ Wq, const float* __restrict__ Wv,
    const float* __restrict__ bk, const float* __restrict__ bq, const float* __restrict__ bv,
    u16* __restrict__ Wkqv, float* __restrict__ bias)
{
  int i = blockIdx.x * 256 + threadIdx.x;
  for (int p = i; p < 768 * 256; p += 64 * 256) {
    float v = (p < 65536) ? Wk[p] : (p < 131072 ? Wq[p - 65536] : Wv[p - 131072]);
    Wkqv[p] = f2bf(v);
  }
  if (i < 768) bias[i] = (i < 256) ? bk[i] : (i < 512 ? bq[i - 256] : bv[i - 512]);
}

// ---------------- transpose x [8][256][HW] f32 -> bf16 [8][HW][256], coalesced reads ----------------
__global__ __launch_bounds__(256) void k_transpose(const float* __restrict__ x, u16* __restrict__ out)
{
  __shared__ u16 T[64 * 264];
  const int t = threadIdx.x;
  const int n = blockIdx.y;
  const int s0 = blockIdx.x * 64;
  const int cg = t >> 4;           // 0..15
  const int sl = (t & 15) * 4;     // s offset 0..60
  #pragma unroll
  for (int i = 0; i < 16; ++i) {
    const int c = i * 16 + cg;
    f32x4 v = *(const f32x4*)(x + ((size_t)n * 256 + c) * HW + s0 + sl);
    #pragma unroll
    for (int j = 0; j < 4; ++j) T[(sl + j) * 264 + c] = f2bf(v[j]);
  }
  __syncthreads();
  const int sr = t >> 2, ch = (t & 3) * 64;
  u16* dst = out + (size_t)n * BSTRIDE + (size_t)(s0 + sr) * 256 + ch;
  const u16* srcl = &T[sr * 264 + ch];
  #pragma unroll
  for (int i = 0; i < 8; ++i) *(s16x8*)(dst + i * 8) = *(const s16x8*)(srcl + i * 8);
}

// ---------------- persistent-A GEMM (K=256 in registers), B streamed via swizzled LDS dbuf --------
// MODE 0: proj, grid 8n x (3mb x 64sb). mb0: exp(keys)+rowsum -> ek,ps ; mb1: head-softmax Q -> qT ;
//         mb2: values -> vb.   MODE 1: attn = Mb*qT^T + br (f32, nt), grid 8n x 64sb.
template<int MODE>
__global__ __launch_bounds__(256, 2) void k_gemmT(
    const u16* __restrict__ A, const u16* __restrict__ B, const float* __restrict__ bias,
    u16* __restrict__ o_ek, u16* __restrict__ o_qT, u16* __restrict__ o_vb,
    float* __restrict__ o_ps, float* __restrict__ o_f32)
{
  __shared__ u16 smem[32768];      // 64 KiB: [2][64 s][256 k]
  const int t = threadIdx.x;
  const int L = blockIdx.x;
  const int n = L & 7;             // batch == XCD
  int mb, sblock;
  if constexpr (MODE == 0) { const int idx = L >> 3; mb = idx % 3; sblock = idx / 3; }
  else                     { mb = 0; sblock = L >> 3; }
  const int lane = t & 63;
  const int l15 = lane & 15, l4 = (lane >> 4) & 3;
  const int w = t >> 6;
  const bool sw = (MODE == 1) || (mb != 1);   // swapped operands -> C is s-major

  const u16* Ag = (MODE == 0) ? A + (size_t)mb * 65536 : A + (size_t)n * 65536;
  const u16* Bg = B + (size_t)n * BSTRIDE;

  // ---- A fragments in registers: 64 m-rows per wave x full K=256 ----
  bf16x8 af[4][8];
  #pragma unroll
  for (int mf = 0; mf < 4; ++mf)
    #pragma unroll
    for (int kc = 0; kc < 8; ++kc)
      af[mf][kc] = *(const bf16x8*)(Ag + (size_t)(w * 64 + mf * 16 + l15) * 256 + kc * 32 + l4 * 8);

  float biasv[4];    // swapped paths: bias at m-col = w*64+mf*16+l15
  f32x4 bq[4];       // Q path: bias at m-row = w*64+mf*16+l4*4+r
  if constexpr (MODE == 0) {
    if (mb != 1) {
      const int bb = (mb == 0) ? 0 : 512;
      #pragma unroll
      for (int mf = 0; mf < 4; ++mf) biasv[mf] = bias[bb + w * 64 + mf * 16 + l15];
    } else {
      #pragma unroll
      for (int mf = 0; mf < 4; ++mf)
        #pragma unroll
        for (int r = 0; r < 4; ++r) bq[mf][r] = bias[256 + w * 64 + mf * 16 + l4 * 4 + r];
    }
  } else {
    #pragma unroll
    for (int mf = 0; mf < 4; ++mf) biasv[mf] = bias[w * 64 + mf * 16 + l15];
  }

  // ---- staging: 16 rows per wave, pre-swizzled source chunks (rule #21) ----
  const int rl_base = w * 16;
  auto STAGE = [&](int buf, int tile) {
    const int s0t = (sblock * 4 + tile) * 64;
    #pragma unroll
    for (int i = 0; i < 8; ++i) {
      const int rl = rl_base + i * 2 + (lane >> 5);
      const size_t gsrc = (size_t)(s0t + rl) * 256 + (size_t)(((lane & 31) ^ (rl & 7)) * 8);
      gld16(Bg + gsrc, smem + buf * 16384 + (rl_base + i * 2) * 256);
    }
  };

  STAGE(0, 0);
  STAGE(1, 1);

  u16* ekb = o_ek + (size_t)n * BSTRIDE;
  u16* vbb = o_vb + (size_t)n * BSTRIDE;
  u16* qtb = o_qT + (size_t)n * BSTRIDE;
  float* ob = o_f32 + (size_t)n * BSTRIDE;

  #pragma unroll
  for (int st = 0; st < 4; ++st) {
    // counted vmcnt: queue = [STAGE(st):8][EPI(st-2):S][STAGE(st+1):8][EPI(st-1):S], S_min=16
    if (st == 0)      asm volatile("s_waitcnt vmcnt(8)" ::: "memory");
    else if (st == 1) asm volatile("s_waitcnt vmcnt(24)" ::: "memory");
    else if (st == 2) asm volatile("s_waitcnt vmcnt(40)" ::: "memory");
    else              asm volatile("s_waitcnt vmcnt(32)" ::: "memory");
    __builtin_amdgcn_s_barrier();

    const int buf = st & 1;
    const u16* Bl = smem + buf * 16384;
    f32x4 acc[4][4] = {};

    if (sw) {
      #pragma unroll
      for (int kc = 0; kc < 8; ++kc) {
        bf16x8 bf[4];
        #pragma unroll
        for (int sf = 0; sf < 4; ++sf)
          bf[sf] = *(const bf16x8*)&Bl[(sf * 16 + l15) * 256 + (((kc * 4 + l4) ^ (l15 & 7)) * 8)];
        __builtin_amdgcn_s_setprio(1);
        #pragma unroll
        for (int sf = 0; sf < 4; ++sf)
          #pragma unroll
          for (int mf = 0; mf < 4; ++mf)
            acc[sf][mf] = __builtin_amdgcn_mfma_f32_16x16x32_bf16(bf[sf], af[mf][kc], acc[sf][mf], 0, 0, 0);
        __builtin_amdgcn_s_setprio(0);
      }
    } else {
      #pragma unroll
      for (int kc = 0; kc < 8; ++kc) {
        bf16x8 bf[4];
        #pragma unroll
        for (int sf = 0; sf < 4; ++sf)
          bf[sf] = *(const bf16x8*)&Bl[(sf * 16 + l15) * 256 + (((kc * 4 + l4) ^ (l15 & 7)) * 8)];
        __builtin_amdgcn_s_setprio(1);
        #pragma unroll
        for (int mf = 0; mf < 4; ++mf)
          #pragma unroll
          for (int sf = 0; sf < 4; ++sf)
            acc[mf][sf] = __builtin_amdgcn_mfma_f32_16x16x32_bf16(af[mf][kc], bf[sf], acc[mf][sf], 0, 0, 0);
        __builtin_amdgcn_s_setprio(0);
      }
    }

    asm volatile("s_waitcnt lgkmcnt(0)" ::: "memory");
    __builtin_amdgcn_s_barrier();
    if (st < 2) STAGE(buf, st + 2);

    // -------- epilogue (S stores counted in vmcnt budget) --------
    const int s0t = (sblock * 4 + st) * 64;
    if constexpr (MODE == 1) {
      // attn: acc[sf][mf][r] at m=w*64+mf*16+l15, s=s0t+sf*16+l4*4+r ; f32 nt stores
      #pragma unroll
      for (int sf = 0; sf < 4; ++sf)
        #pragma unroll
        for (int mf = 0; mf < 4; ++mf) {
          f32x4 o = acc[sf][mf] + biasv[mf];
          __builtin_nontemporal_store(
              o, (f32x4*)(ob + (size_t)(w * 64 + mf * 16 + l15) * HW + s0t + sf * 16 + l4 * 4));
        }
    } else if (mb == 0) {
      // keys: exp + packed bf16 stores + rowsum partials
      float prow[4] = {0.f, 0.f, 0.f, 0.f};
      #pragma unroll
      for (int sf = 0; sf < 4; ++sf)
        #pragma unroll
        for (int mf = 0; mf < 4; ++mf) {
          f32x4 e;
          #pragma unroll
          for (int r = 0; r < 4; ++r) e[r] = __expf(acc[sf][mf][r] + biasv[mf]);
          prow[mf] += e[0] + e[1] + e[2] + e[3];
          s16x4 pk;
          #pragma unroll
          for (int r = 0; r < 4; ++r) pk[r] = (short)f2bf(e[r]);
          *(s16x4*)(ekb + (size_t)(w * 64 + mf * 16 + l15) * HW + s0t + sf * 16 + l4 * 4) = pk;
        }
      const int stile = sblock * 4 + st;
      #pragma unroll
      for (int mf = 0; mf < 4; ++mf) {
        float v = prow[mf];
        v += __shfl_xor(v, 16); v += __shfl_xor(v, 32);
        prow[mf] = v;
      }
      if (l4 == 0) {
        #pragma unroll
        for (int mf = 0; mf < 4; ++mf)
          o_ps[(size_t)stile * 2048 + n * 256 + w * 64 + mf * 16 + l15] = prow[mf];
      }
    } else if (mb == 1) {
      // queries (unswapped): acc[mf][sf][r] at m=w*64+mf*16+l4*4+r, s=s0t+sf*16+l15
      #pragma unroll
      for (int mf = 0; mf < 4; ++mf)
        #pragma unroll
        for (int sf = 0; sf < 4; ++sf)
          #pragma unroll
          for (int r = 0; r < 4; ++r) acc[mf][sf][r] = __expf(acc[mf][sf][r] + bq[mf][r]);
      #pragma unroll
      for (int sf = 0; sf < 4; ++sf) {
        float h0 = 0.f, h1 = 0.f;
        #pragma unroll
        for (int r = 0; r < 4; ++r) {
          h0 += acc[0][sf][r] + acc[1][sf][r];
          h1 += acc[2][sf][r] + acc[3][sf][r];
        }
        h0 += __shfl_xor(h0, 16); h0 += __shfl_xor(h0, 32);
        h1 += __shfl_xor(h1, 16); h1 += __shfl_xor(h1, 32);
        const float i0 = 1.f / h0, i1 = 1.f / h1;
        #pragma unroll
        for (int mf = 0; mf < 4; ++mf) {
          const float iv = (mf < 2) ? i0 : i1;
          s16x4 pk;
          #pragma unroll
          for (int r = 0; r < 4; ++r) pk[r] = (short)f2bf(acc[mf][sf][r] * iv);
          *(s16x4*)(qtb + (size_t)(s0t + sf * 16 + l15) * 256 + w * 64 + mf * 16 + l4 * 4) = pk;
        }
      }
    } else {
      // values: packed bf16 stores
      #pragma unroll
      for (int sf = 0; sf < 4; ++sf)
        #pragma unroll
        for (int mf = 0; mf < 4; ++mf) {
          s16x4 pk;
          #pragma unroll
          for (int r = 0; r < 4; ++r) pk[r] = (short)f2bf(acc[sf][mf][r] + biasv[mf]);
          *(s16x4*)(vbb + (size_t)(w * 64 + mf * 16 + l15) * HW + s0t + sf * 16 + l4 * 4) = pk;
        }
    }
  }
}

// ---------------- reduce rowsum partials -> inverse ----------------
__global__ __launch_bounds__(256) void k_inv(const float* __restrict__ ps, float* __restrict__ ise)
{
  const int i = blockIdx.x * 256 + threadIdx.x;   // 2048
  float s = 0.f;
  for (int b = 0; b < 256; ++b) s += ps[(size_t)b * 2048 + i];
  ise[i] = 1.f / s;
}

// ---------------- ctx split-K partials + fused attention-map partials ----------------
__global__ __launch_bounds__(64) void k_ctx_part(
    const u16* __restrict__ ek, const u16* __restrict__ vb, const float* __restrict__ ise,
    float* __restrict__ cpart, float* __restrict__ mpart)
{
  const int blk = blockIdx.x;            // nh*64 + chunk
  const int chunk = blk & 63, nh = blk >> 6;
  const int h = nh & 7, n = nh >> 3;
  const int lane = threadIdx.x;
  const int l15 = lane & 15, l4 = lane >> 4;
  const u16* kb = ek + ((size_t)n * 256 + h * 32) * HW;
  const u16* vv = vb + ((size_t)n * 256 + h * 32) * HW;
  const float iv0 = ise[n * 256 + h * 32 + l15];
  const float iv1 = ise[n * 256 + h * 32 + 16 + l15];
  f32x4 acc[2][2] = {};
  float macc[8][8] = {};
  const int sbase = chunk * 256 + l4 * 8;
  #pragma unroll
  for (int ks = 0; ks < 8; ++ks) {
    const int sb = sbase + ks * 32;
    bf16x8 ef[2], vf[2];
    #pragma unroll
    for (int g = 0; g < 2; ++g) {
      ef[g] = *(const bf16x8*)(kb + (size_t)(g * 16 + l15) * HW + sb);
      vf[g] = *(const bf16x8*)(vv + (size_t)(g * 16 + l15) * HW + sb);
    }
    #pragma unroll
    for (int j = 0; j < 8; ++j)
      macc[ks][j] = fmaf(iv0, (float)ef[0][j], fmaf(iv1, (float)ef[1][j], macc[ks][j]));
    #pragma unroll
    for (int a = 0; a < 2; ++a)
      #pragma unroll
      for (int b = 0; b < 2; ++b)
        acc[a][b] = __builtin_amdgcn_mfma_f32_16x16x32_bf16(ef[a], vf[b], acc[a][b], 0, 0, 0);
  }
  float* op = cpart + (size_t)blk * 1024;
  #pragma unroll
  for (int a = 0; a < 2; ++a)
    #pragma unroll
    for (int b = 0; b < 2; ++b)
      #pragma unroll
      for (int r = 0; r < 4; ++r)
        op[(a * 16 + l4 * 4 + r) * 32 + b * 16 + l15] = acc[a][b][r];
  #pragma unroll
  for (int ks = 0; ks < 8; ++ks)
    #pragma unroll
    for (int j = 0; j < 8; ++j) {
      float v = macc[ks][j];
      v += __shfl_xor(v, 1); v += __shfl_xor(v, 2);
      v += __shfl_xor(v, 4); v += __shfl_xor(v, 8);
      macc[ks][j] = v;
    }
  if (l15 == 0) {
    float* mp = mpart + ((size_t)h * 8 + n) * HW + sbase;
    #pragma unroll
    for (int ks = 0; ks < 8; ++ks) {
      f32x4 a = {macc[ks][0], macc[ks][1], macc[ks][2], macc[ks][3]};
      f32x4 b = {macc[ks][4], macc[ks][5], macc[ks][6], macc[ks][7]};
      *(f32x4*)(mp + ks * 32)     = a;
      *(f32x4*)(mp + ks * 32 + 4) = b;
    }
  }
}

// ---------------- reduce ctx partials, normalize; emit context_last (h==7) ----------------
__global__ __launch_bounds__(256) void k_ctx_reduce(
    const float* __restrict__ cpart, const float* __restrict__ ise,
    float* __restrict__ ctx, float* __restrict__ dctx)
{
  const int nh = blockIdx.x, n = nh >> 3, h = nh & 7, t = threadIdx.x;
  f32x4 a = {};
  for (int c = 0; c < 64; ++c) a += *(const f32x4*)(cpart + ((size_t)nh * 64 + c) * 1024 + t * 4);
  const float inv = ise[n * 256 + h * 32 + (t >> 3)];
  a *= inv;
  *(f32x4*)(ctx + (size_t)nh * 1024 + t * 4) = a;
  if (h == 7) *(f32x4*)(dctx + (size_t)n * 1024 + t * 4) = a;
}

// ---------------- M[n][o][h*32+k] = sum_v Wr[o][h*32+v] * ctx[n][h][k][v] ----------------
__global__ __launch_bounds__(256) void k_mmat(
    const float* __restrict__ ctx, const float* __restrict__ Wr, u16* __restrict__ Mb)
{
  const int nh = blockIdx.x, n = nh >> 3, h = nh & 7, o = threadIdx.x;
  __shared__ float cl[1024];
  #pragma unroll
  for (int i = 0; i < 4; ++i) cl[o + i * 256] = ctx[(size_t)nh * 1024 + o + i * 256];
  __syncthreads();
  float wr[32];
  const float* wp = Wr + (size_t)o * 256 + h * 32;
  #pragma unroll
  for (int v = 0; v < 32; ++v) wr[v] = wp[v];
  u16* mp = Mb + ((size_t)n * 256 + o) * 256 + h * 32;
  #pragma unroll 4
  for (int k = 0; k < 32; ++k) {
    float s = 0.f;
    #pragma unroll
    for (int v = 0; v < 32; ++v) s += wr[v] * cl[k * 32 + v];
    mp[k] = f2bf(s);
  }
}

// ---------------- attention_map: sum 8 head partials, /256 ----------------
__global__ __launch_bounds__(256) void k_map_reduce(const float* __restrict__ mpart, float* __restrict__ dmap)
{
  const int i = blockIdx.x * 256 + threadIdx.x;   // 32768 threads, f32x4 each
  f32x4 a = {};
  #pragma unroll
  for (int h = 0; h < 8; ++h) a += *(const f32x4*)(mpart + (size_t)h * 131072 + (size_t)i * 4);
  a *= (1.0f / 256.0f);
  *(f32x4*)(dmap + (size_t)i * 4) = a;
}

extern "C" void kernel_launch(void* const* d_in, const int* in_sizes, int n_in,
                              void* d_out, int out_size, void* d_ws, size_t ws_size,
                              hipStream_t stream)
{
  (void)in_sizes; (void)n_in; (void)out_size; (void)ws_size;
  const float* x  = (const float*)d_in[0];
  const float* Wk = (const float*)d_in[1];
  const float* bk = (const float*)d_in[2];
  const float* Wq = (const float*)d_in[3];
  const float* bq = (const float*)d_in[4];
  const float* Wv = (const float*)d_in[5];
  const float* bv = (const float*)d_in[6];
  const float* Wr = (const float*)d_in[7];
  const float* br = (const float*)d_in[8];

  char* ws = (char*)d_ws;
  u16*   xbT  = (u16*)(ws + oXBT);
  u16*   ek   = (u16*)(ws + oEK);
  u16*   qT   = (u16*)(ws + oQT);
  u16*   vb   = (u16*)(ws + oVB);
  u16*   Wkqv = (u16*)(ws + oWK);
  float* bias = (float*)(ws + oBIAS);
  float* ise  = (float*)(ws + oISE);
  float* ps   = (float*)(ws + oPS);
  float* ctx  = (float*)(ws + oCTX);
  u16*   Mb   = (u16*)(ws + oMB);
  float* cpart= (float*)(ws + oCPART);
  float* mpart= (float*)(ws + oMPART);

  float* attn = (float*)d_out;                    // [8][256][HW]
  float* dctx = (float*)d_out + 33554432;         // [8][32][32]
  float* dmap = (float*)d_out + 33562624;         // [8][HW]

  k_prep<<<64, 256, 0, stream>>>(Wk, Wq, Wv, bk, bq, bv, Wkqv, bias);
  k_transpose<<<dim3(256, 8), 256, 0, stream>>>(x, xbT);
  k_gemmT<0><<<1536, 256, 0, stream>>>(Wkqv, xbT, bias, ek, qT, vb, ps, nullptr);
  k_inv<<<8, 256, 0, stream>>>(ps, ise);
  k_ctx_part<<<4096, 64, 0, stream>>>(ek, vb, ise, cpart, mpart);
  k_ctx_reduce<<<64, 256, 0, stream>>>(cpart, ise, ctx, dctx);
  k_mmat<<<64, 256, 0, stream>>>(ctx, Wr, Mb);
  k_map_reduce<<<128, 256, 0, stream>>>(mpart, dmap);
  k_gemmT<1><<<512, 256, 0, stream>>>(Mb, qT, br, nullptr, nullptr, nullptr, nullptr, attn);
}